// Round 1
// baseline (102.320 us; speedup 1.0000x reference)
//
#include <hip/hip_runtime.h>

// DropStripes: out[b,t,c] = x[b,t,c] * keep[b,c]
// keep[b,c] = !any_s( c in [bgn[b,s], bgn[b,s]+dist[b,s]) )
// dist = floor(u_dist*64), bgn = floor(u_bgn*(512-dist))
//
// x: (64, 2048, 512) fp32. Pure memory-bound: 512 MB total traffic.

__global__ void DropStripes_kernel(const float4* __restrict__ x,
                                   const float* __restrict__ u_dist,
                                   const float* __restrict__ u_bgn,
                                   float4* __restrict__ out,
                                   int n4) {
    constexpr int W4 = 512 / 4;              // 128 float4 per row
    // per-batch float4 count = 2048*512/4 = 262144 = 2^18
    int idx = blockIdx.x * blockDim.x + threadIdx.x;
    int stride = gridDim.x * blockDim.x;
    for (int i = idx; i < n4; i += stride) {
        int b  = i >> 18;                    // batch index
        int c0 = (i & (W4 - 1)) << 2;        // first channel of this float4

        // Stripe params: tiny (512 B) arrays, L1-resident.
        float ud0 = u_dist[2 * b];
        float ud1 = u_dist[2 * b + 1];
        float ub0 = u_bgn[2 * b];
        float ub1 = u_bgn[2 * b + 1];

        int dist0 = (int)floorf(ud0 * 64.0f);
        int dist1 = (int)floorf(ud1 * 64.0f);
        int bgn0  = (int)floorf(ub0 * (float)(512 - dist0));
        int bgn1  = (int)floorf(ub1 * (float)(512 - dist1));
        int end0  = bgn0 + dist0;
        int end1  = bgn1 + dist1;

        float4 v = x[i];
        float* vp = reinterpret_cast<float*>(&v);
        #pragma unroll
        for (int j = 0; j < 4; ++j) {
            int c = c0 + j;
            bool drop = (c >= bgn0 && c < end0) || (c >= bgn1 && c < end1);
            vp[j] = drop ? 0.0f : vp[j];
        }
        out[i] = v;
    }
}

extern "C" void kernel_launch(void* const* d_in, const int* in_sizes, int n_in,
                              void* d_out, int out_size, void* d_ws, size_t ws_size,
                              hipStream_t stream) {
    const float* x      = (const float*)d_in[0];
    const float* u_dist = (const float*)d_in[1];
    const float* u_bgn  = (const float*)d_in[2];
    float* out          = (float*)d_out;

    int n4 = out_size / 4;                   // 16,777,216 float4
    int block = 256;
    int grid = 8192;                          // grid-stride, ~32 blocks/CU worth of waves
    DropStripes_kernel<<<grid, block, 0, stream>>>(
        (const float4*)x, u_dist, u_bgn, (float4*)out, n4);
}